// Round 5
// baseline (248.303 us; speedup 1.0000x reference)
//
#include <hip/hip_runtime.h>
#include <hip/hip_bf16.h>

// SelfBiLayer B=256,L=2048,E=64,DA=64,R=32 -- MFMA round 5.
// Round-4 lesson: all pipes <20% busy -> latency-serialized, not
// throughput-bound. Fixes:
//  * x read ONCE (coalesced token rows); xT built via 16 ds_write_b16
//    column-scatters with 8*g XOR swizzle (2-way max = free; reader b128
//    stays aligned: XOR is mult-of-8 on a bit-3-constant group).
//  * sub-chunk 64 tokens -> LDS 23.6 KB -> 5 blocks/CU (launch_bounds 256,5).
//  * ssum partials via __shfl_xor over g (lane bits 4/5), no LDS array.
// Per block: (b, 256-token chunk), 4 sub-chunks of 64 tokens, 4 waves.

#define B_  256
#define L_  2048
#define E_  64
#define DA_ 64
#define R_  32
#define CH_ 8
#define NS_ 4
#define TL_ 64

typedef __attribute__((ext_vector_type(8))) short bf16x8;
typedef __attribute__((ext_vector_type(4))) float f32x4;

// LDS (dword units). Pitches mult-of-4 words keep b128 alignment.
#define HS_P 36
#define XT_P 36
#define AS_P 36
#define HS_W (64 * HS_P)     // 2304
#define XT_W (64 * XT_P)     // 2304
#define AS_W (32 * AS_P)     // 1152
// + 128 words ssl -> 5888 words = 23552 B -> LDS allows 6 blocks/CU

__device__ __forceinline__ unsigned pk(float a, float b) {
    __hip_bfloat162 h = __float22bfloat162_rn(float2{a, b});
    union { __hip_bfloat162 h2; unsigned u; } cv; cv.h2 = h;
    return cv.u;
}
__device__ __forceinline__ float bflo(unsigned u) { return __uint_as_float(u << 16); }
__device__ __forceinline__ float bfhi(unsigned u) { return __uint_as_float(u & 0xFFFF0000u); }
__device__ __forceinline__ float fast_tanh(float v) {
    float e = __builtin_amdgcn_exp2f(v * 2.885390082f);
    float r = __builtin_amdgcn_rcpf(e + 1.0f);
    return fmaf(-2.0f, r, 1.0f);
}
__device__ __forceinline__ float fast_exp(float v) {
    return __builtin_amdgcn_exp2f(v * 1.442695041f);
}

__launch_bounds__(256, 5)
__global__ void selfbi_main(const float* __restrict__ x,
                            const float* __restrict__ mask,
                            const float* __restrict__ W1,
                            const float* __restrict__ W2,
                            float* __restrict__ accp,
                            float* __restrict__ ssump) {
    __shared__ __align__(16) unsigned smem[HS_W + XT_W + AS_W + 128];
    unsigned* hsw = smem;                  // H token-major bf16 (wave-private rows)
    unsigned* xtw = smem + HS_W;           // x e-major bf16, token-swizzled
    unsigned* asw = xtw + XT_W;            // asT[r][t] bf16
    float*    ssl = (float*)(asw + AS_W);  // per-wave ssum partials (epilogue only)

    const int b    = blockIdx.x;
    const int c    = blockIdx.y;
    const int tid  = threadIdx.x;
    const int w    = tid >> 6;
    const int lane = tid & 63;
    const int g    = lane >> 4;     // k-octet group
    const int ml   = lane & 15;     // m/n lane

    // ---- W1 A-frags + W2^T B-frags in registers (once per block) ----
    bf16x8 w1f[4][2], w2f[2][2];
    #pragma unroll
    for (int mt = 0; mt < 4; ++mt)
        #pragma unroll
        for (int kb = 0; kb < 2; ++kb) {
            const float* p = W1 + (16 * mt + ml) * E_ + 32 * kb + 8 * g;
            float4 a = *(const float4*)p, bb = *(const float4*)(p + 4);
            union { bf16x8 s; unsigned u[4]; } cv;
            cv.u[0] = pk(a.x, a.y); cv.u[1] = pk(a.z, a.w);
            cv.u[2] = pk(bb.x, bb.y); cv.u[3] = pk(bb.z, bb.w);
            w1f[mt][kb] = cv.s;
        }
    #pragma unroll
    for (int nt = 0; nt < 2; ++nt)
        #pragma unroll
        for (int kb = 0; kb < 2; ++kb) {
            const float* p = W2 + (16 * nt + ml) * DA_ + 32 * kb + 8 * g;
            float4 a = *(const float4*)p, bb = *(const float4*)(p + 4);
            union { bf16x8 s; unsigned u[4]; } cv;
            cv.u[0] = pk(a.x, a.y); cv.u[1] = pk(a.z, a.w);
            cv.u[2] = pk(bb.x, bb.y); cv.u[3] = pk(bb.z, bb.w);
            w2f[nt][kb] = cv.s;
        }

    f32x4 c3[2] = {f32x4{0,0,0,0}, f32x4{0,0,0,0}};
    float sswav0 = 0.0f, sswav1 = 0.0f;

    const int trow = 16 * w + ml;          // this thread's token within sub-chunk
    const int thalf = trow >> 1, tbyte = trow & 1;

    for (int s = 0; s < NS_; ++s) {
        if (s) __syncthreads();    // xT/asT rewrite vs prev sub-chunk GEMM3 readers

        const int    l0    = c * (NS_ * TL_) + s * TL_;
        const size_t xbase = ((size_t)b * L_ + l0) * E_;

        // ---- global loads: ONE coalesced pass over x token rows + mask ----
        const float* xr = x + xbase + (size_t)trow * E_;
        float4 gx[2][2];
        gx[0][0] = *(const float4*)(xr + 8 * g);
        gx[0][1] = *(const float4*)(xr + 8 * g + 4);
        gx[1][0] = *(const float4*)(xr + 32 + 8 * g);
        gx[1][1] = *(const float4*)(xr + 32 + 8 * g + 4);
        float4 mk = *(const float4*)(mask + b * L_ + l0 + 16 * w + 4 * g);

        // ---- pack bf16 B-frags for GEMM1 (same values feed xT) ----
        bf16x8 xf[2];
        union { bf16x8 s; unsigned u[4]; } xc[2];
        #pragma unroll
        for (int kb = 0; kb < 2; ++kb) {
            xc[kb].u[0] = pk(gx[kb][0].x, gx[kb][0].y);
            xc[kb].u[1] = pk(gx[kb][0].z, gx[kb][0].w);
            xc[kb].u[2] = pk(gx[kb][1].x, gx[kb][1].y);
            xc[kb].u[3] = pk(gx[kb][1].z, gx[kb][1].w);
            xf[kb] = xc[kb].s;
        }

        // ---- xT: e-major, token-column scatter, swizzle word^(8g) ----
        #pragma unroll
        for (int kb = 0; kb < 2; ++kb)
            #pragma unroll
            for (int i = 0; i < 4; ++i) {
                const int e0 = 32 * kb + 8 * g + 2 * i;
                const int wd = thalf ^ (8 * g);     // sigma(e0)=g
                ((unsigned short*)&xtw[e0 * XT_P + wd])[tbyte] =
                    (unsigned short)(xc[kb].u[i] & 0xFFFF);
                ((unsigned short*)&xtw[(e0 + 1) * XT_P + wd])[tbyte] =
                    (unsigned short)(xc[kb].u[i] >> 16);
            }

        // ---- GEMM1: H^T tile (this wave's 16 tokens) ----
        f32x4 c1[4] = {f32x4{0,0,0,0}, f32x4{0,0,0,0}, f32x4{0,0,0,0}, f32x4{0,0,0,0}};
        #pragma unroll
        for (int kb = 0; kb < 2; ++kb)
            #pragma unroll
            for (int mt = 0; mt < 4; ++mt)
                c1[mt] = __builtin_amdgcn_mfma_f32_16x16x32_bf16(
                    w1f[mt][kb], xf[kb], c1[mt], 0, 0, 0);

        // ---- tanh -> hs (token-major, wave-private row) ----
        #pragma unroll
        for (int mt = 0; mt < 4; ++mt) {
            float h0 = fast_tanh(c1[mt][0]);
            float h1 = fast_tanh(c1[mt][1]);
            float h2 = fast_tanh(c1[mt][2]);
            float h3 = fast_tanh(c1[mt][3]);
            uint2 u; u.x = pk(h0, h1); u.y = pk(h2, h3);
            *(uint2*)&hsw[trow * HS_P + 8 * mt + 2 * g] = u;   // d0 = 16mt+4g
        }

        // ---- GEMM2': Q[t][r] = H @ W2^T (A rows wave-local, no barrier) ----
        f32x4 c2[2] = {f32x4{0,0,0,0}, f32x4{0,0,0,0}};
        #pragma unroll
        for (int kb = 0; kb < 2; ++kb) {
            bf16x8 af = *(bf16x8*)&hsw[trow * HS_P + 16 * kb + 4 * g];
            #pragma unroll
            for (int nt = 0; nt < 2; ++nt)
                c2[nt] = __builtin_amdgcn_mfma_f32_16x16x32_bf16(
                    af, w2f[nt][kb], c2[nt], 0, 0, 0);
        }

        // ---- exp*m -> asT (b64) + ssum partials via shfl over g ----
        float part0, part1;
        {
            const int tw = 8 * w + 2 * g;          // tokens 16w+4g.. -> word pair
            float a0 = fast_exp(c2[0][0]) * mk.x;
            float a1 = fast_exp(c2[0][1]) * mk.y;
            float a2 = fast_exp(c2[0][2]) * mk.z;
            float a3 = fast_exp(c2[0][3]) * mk.w;
            uint2 u; u.x = pk(a0, a1); u.y = pk(a2, a3);
            *(uint2*)&asw[ml * AS_P + tw] = u;
            part0 = bflo(u.x) + bfhi(u.x) + bflo(u.y) + bfhi(u.y);
            a0 = fast_exp(c2[1][0]) * mk.x;
            a1 = fast_exp(c2[1][1]) * mk.y;
            a2 = fast_exp(c2[1][2]) * mk.z;
            a3 = fast_exp(c2[1][3]) * mk.w;
            u.x = pk(a0, a1); u.y = pk(a2, a3);
            *(uint2*)&asw[(16 + ml) * AS_P + tw] = u;
            part1 = bflo(u.x) + bfhi(u.x) + bflo(u.y) + bfhi(u.y);
        }
        part0 += __shfl_xor(part0, 16); part0 += __shfl_xor(part0, 32);
        part1 += __shfl_xor(part1, 16); part1 += __shfl_xor(part1, 32);
        sswav0 += part0; sswav1 += part1;

        __syncthreads();   // asT + xT visible to all waves

        // ---- GEMM3: acc[r][e] += a^T @ x ----
        {
            const int erow = 16 * w + ml;
            const int esw  = 8 * ((erow >> 3) & 3);
            #pragma unroll
            for (int kb = 0; kb < 2; ++kb) {
                bf16x8 bf = *(bf16x8*)&xtw[erow * XT_P + ((16 * kb + 4 * g) ^ esw)];
                #pragma unroll
                for (int mt = 0; mt < 2; ++mt) {
                    bf16x8 af = *(bf16x8*)&asw[(16 * mt + ml) * AS_P + 16 * kb + 4 * g];
                    c3[mt] = __builtin_amdgcn_mfma_f32_16x16x32_bf16(af, bf, c3[mt], 0, 0, 0);
                }
            }
        }
    }

    // ---- epilogue ----
    const size_t obase = (size_t)(b * CH_ + c) * (R_ * E_);
    const int e = 16 * w + ml;
    #pragma unroll
    for (int mt = 0; mt < 2; ++mt)
        #pragma unroll
        for (int reg = 0; reg < 4; ++reg) {
            const int r = 16 * mt + 4 * g + reg;
            accp[obase + r * E_ + e] = c3[mt][reg];
        }
    if (g == 0) {
        ssl[w * 32 + ml]      = sswav0;
        ssl[w * 32 + 16 + ml] = sswav1;
    }
    __syncthreads();
    if (tid < 32)
        ssump[(b * CH_ + c) * R_ + tid] =
            ssl[tid] + ssl[32 + tid] + ssl[64 + tid] + ssl[96 + tid];
}

__launch_bounds__(256, 4)
__global__ void selfbi_reduce(const float* __restrict__ accp,
                              const float* __restrict__ ssump,
                              float* __restrict__ out) {
    const int of = blockIdx.x * 256 + threadIdx.x;  // flat (b,r,e)
    const int b  = of >> 11;
    const int o  = of & 2047;
    const int r  = o >> 6;
    float num = 0.f, den = 0.f;
    #pragma unroll
    for (int cc = 0; cc < CH_; ++cc) {
        num += accp[((size_t)(b * CH_ + cc)) * (R_ * E_) + o];
        den += ssump[(b * CH_ + cc) * R_ + r];
    }
    out[of] = num / den;
}

extern "C" void kernel_launch(void* const* d_in, const int* in_sizes, int n_in,
                              void* d_out, int out_size, void* d_ws, size_t ws_size,
                              hipStream_t stream) {
    const float* x    = (const float*)d_in[0];   // (B,L,E)
    const float* mask = (const float*)d_in[1];   // (B,L)
    const float* W1   = (const float*)d_in[2];   // (DA,E)
    const float* W2   = (const float*)d_in[3];   // (R,DA)
    float* out        = (float*)d_out;           // (B,R,E)

    float* accp  = (float*)d_ws;                        // B*CH*R*E fp32
    float* ssump = accp + (size_t)B_ * CH_ * R_ * E_;   // B*CH*R fp32

    selfbi_main<<<dim3(B_, CH_), dim3(256), 0, stream>>>(x, mask, W1, W2, accp, ssump);
    selfbi_reduce<<<dim3((B_ * R_ * E_) / 256), dim3(256), 0, stream>>>(accp, ssump, out);
}

// Round 6
// 207.684 us; speedup vs baseline: 1.1956x; 1.1956x over previous
//
#include <hip/hip_runtime.h>
#include <hip/hip_bf16.h>

// SelfBiLayer B=256,L=2048,E=64,DA=64,R=32 -- MFMA round 6.
// Round-5 lesson: launch_bounds(256,5) forced VGPR=48 < ~56 persistent regs
// -> scratch spills (+70MB WRITE). Fixes:
//  * launch_bounds(256,4): 128-VGPR cap, no spills, 4 blocks/CU.
//  * double-buffered xT/asT -> ONE barrier per 64-token sub-chunk
//    (GEMM3(s) -> staging(s+1) -> barrier(s+1) makes buf reuse at s+2 safe).
//  * global loads for s+1 issued before GEMM1(s) -> VMEM latency hides
//    under GEMM1/tanh/GEMM2 compute.
// Per block: (b, 256-token chunk), 4 sub-chunks of 64 tokens, 4 waves.

#define B_  256
#define L_  2048
#define E_  64
#define DA_ 64
#define R_  32
#define CH_ 8
#define NS_ 4
#define TL_ 64

typedef __attribute__((ext_vector_type(8))) short bf16x8;
typedef __attribute__((ext_vector_type(4))) float f32x4;

// LDS (dword units). Pitches mult-of-4 words keep b128 alignment.
#define HS_P 36
#define XT_P 36
#define AS_P 36
#define HS_W (64 * HS_P)     // 2304
#define XT_W (64 * XT_P)     // 2304 per buffer
#define AS_W (32 * AS_P)     // 1152 per buffer
// hs + 2*xt + 2*as + 128 ssl = 9344 words = 37376 B -> 4 blocks/CU

__device__ __forceinline__ unsigned pk(float a, float b) {
    __hip_bfloat162 h = __float22bfloat162_rn(float2{a, b});
    union { __hip_bfloat162 h2; unsigned u; } cv; cv.h2 = h;
    return cv.u;
}
__device__ __forceinline__ float bflo(unsigned u) { return __uint_as_float(u << 16); }
__device__ __forceinline__ float bfhi(unsigned u) { return __uint_as_float(u & 0xFFFF0000u); }
__device__ __forceinline__ float fast_tanh(float v) {
    float e = __builtin_amdgcn_exp2f(v * 2.885390082f);
    float r = __builtin_amdgcn_rcpf(e + 1.0f);
    return fmaf(-2.0f, r, 1.0f);
}
__device__ __forceinline__ float fast_exp(float v) {
    return __builtin_amdgcn_exp2f(v * 1.442695041f);
}

__launch_bounds__(256, 4)
__global__ void selfbi_main(const float* __restrict__ x,
                            const float* __restrict__ mask,
                            const float* __restrict__ W1,
                            const float* __restrict__ W2,
                            float* __restrict__ accp,
                            float* __restrict__ ssump) {
    __shared__ __align__(16) unsigned smem[HS_W + 2 * XT_W + 2 * AS_W + 128];
    unsigned* hsw  = smem;                       // H token-major (wave-private rows)
    unsigned* xtw0 = smem + HS_W;                // x e-major, double-buffered
    unsigned* asw0 = xtw0 + 2 * XT_W;            // asT[r][t], double-buffered
    float*    ssl  = (float*)(asw0 + 2 * AS_W);  // per-wave ssum partials (epilogue)

    const int b    = blockIdx.x;
    const int c    = blockIdx.y;
    const int tid  = threadIdx.x;
    const int w    = tid >> 6;
    const int lane = tid & 63;
    const int g    = lane >> 4;     // k-octet group
    const int ml   = lane & 15;     // m/n lane

    // ---- W1 A-frags + W2^T B-frags in registers (once per block) ----
    bf16x8 w1f[4][2], w2f[2][2];
    #pragma unroll
    for (int mt = 0; mt < 4; ++mt)
        #pragma unroll
        for (int kb = 0; kb < 2; ++kb) {
            const float* p = W1 + (16 * mt + ml) * E_ + 32 * kb + 8 * g;
            float4 a = *(const float4*)p, bb = *(const float4*)(p + 4);
            union { bf16x8 s; unsigned u[4]; } cv;
            cv.u[0] = pk(a.x, a.y); cv.u[1] = pk(a.z, a.w);
            cv.u[2] = pk(bb.x, bb.y); cv.u[3] = pk(bb.z, bb.w);
            w1f[mt][kb] = cv.s;
        }
    #pragma unroll
    for (int nt = 0; nt < 2; ++nt)
        #pragma unroll
        for (int kb = 0; kb < 2; ++kb) {
            const float* p = W2 + (16 * nt + ml) * DA_ + 32 * kb + 8 * g;
            float4 a = *(const float4*)p, bb = *(const float4*)(p + 4);
            union { bf16x8 s; unsigned u[4]; } cv;
            cv.u[0] = pk(a.x, a.y); cv.u[1] = pk(a.z, a.w);
            cv.u[2] = pk(bb.x, bb.y); cv.u[3] = pk(bb.z, bb.w);
            w2f[nt][kb] = cv.s;
        }

    f32x4 c3[2] = {f32x4{0,0,0,0}, f32x4{0,0,0,0}};
    float sswav0 = 0.0f, sswav1 = 0.0f;

    const int trow  = 16 * w + ml;          // this thread's token within sub-chunk
    const int thalf = trow >> 1, tbyte = trow & 1;
    const size_t cbase = ((size_t)b * L_ + c * (NS_ * TL_)) * E_;
    const int    mbase = b * L_ + c * (NS_ * TL_);

    // ---- prologue: loads for sub-chunk 0 ----
    float4 gx[2][2], mk;
    {
        const float* xr = x + cbase + (size_t)trow * E_ + 8 * g;
        gx[0][0] = *(const float4*)xr;
        gx[0][1] = *(const float4*)(xr + 4);
        gx[1][0] = *(const float4*)(xr + 32);
        gx[1][1] = *(const float4*)(xr + 36);
        mk = *(const float4*)(mask + mbase + 16 * w + 4 * g);
    }

    for (int s = 0; s < NS_; ++s) {
        unsigned* xtw = xtw0 + (s & 1) * XT_W;
        unsigned* asw = asw0 + (s & 1) * AS_W;

        // ---- pack bf16 B-frags for GEMM1 (same values feed xT) ----
        bf16x8 xf[2];
        union { bf16x8 s; unsigned u[4]; } xc[2];
        #pragma unroll
        for (int kb = 0; kb < 2; ++kb) {
            xc[kb].u[0] = pk(gx[kb][0].x, gx[kb][0].y);
            xc[kb].u[1] = pk(gx[kb][0].z, gx[kb][0].w);
            xc[kb].u[2] = pk(gx[kb][1].x, gx[kb][1].y);
            xc[kb].u[3] = pk(gx[kb][1].z, gx[kb][1].w);
            xf[kb] = xc[kb].s;
        }

        // ---- issue NEXT sub-chunk's global loads (hide under GEMM1/2) ----
        float4 gxn[2][2], mkn;
        if (s + 1 < NS_) {
            const float* xr = x + cbase + (size_t)((s + 1) * TL_ + trow) * E_ + 8 * g;
            gxn[0][0] = *(const float4*)xr;
            gxn[0][1] = *(const float4*)(xr + 4);
            gxn[1][0] = *(const float4*)(xr + 32);
            gxn[1][1] = *(const float4*)(xr + 36);
            mkn = *(const float4*)(mask + mbase + (s + 1) * TL_ + 16 * w + 4 * g);
        }

        // ---- xT: e-major, token-column scatter, swizzle word^(8g) ----
        #pragma unroll
        for (int kb = 0; kb < 2; ++kb)
            #pragma unroll
            for (int i = 0; i < 4; ++i) {
                const int e0 = 32 * kb + 8 * g + 2 * i;
                const int wd = thalf ^ (8 * g);
                ((unsigned short*)&xtw[e0 * XT_P + wd])[tbyte] =
                    (unsigned short)(xc[kb].u[i] & 0xFFFF);
                ((unsigned short*)&xtw[(e0 + 1) * XT_P + wd])[tbyte] =
                    (unsigned short)(xc[kb].u[i] >> 16);
            }

        // ---- GEMM1: H^T tile (this wave's 16 tokens) ----
        f32x4 c1[4] = {f32x4{0,0,0,0}, f32x4{0,0,0,0}, f32x4{0,0,0,0}, f32x4{0,0,0,0}};
        #pragma unroll
        for (int kb = 0; kb < 2; ++kb)
            #pragma unroll
            for (int mt = 0; mt < 4; ++mt)
                c1[mt] = __builtin_amdgcn_mfma_f32_16x16x32_bf16(
                    w1f[mt][kb], xf[kb], c1[mt], 0, 0, 0);

        // ---- tanh -> hs (token-major, wave-private row) ----
        #pragma unroll
        for (int mt = 0; mt < 4; ++mt) {
            float h0 = fast_tanh(c1[mt][0]);
            float h1 = fast_tanh(c1[mt][1]);
            float h2 = fast_tanh(c1[mt][2]);
            float h3 = fast_tanh(c1[mt][3]);
            uint2 u; u.x = pk(h0, h1); u.y = pk(h2, h3);
            *(uint2*)&hsw[trow * HS_P + 8 * mt + 2 * g] = u;   // d0 = 16mt+4g
        }

        // ---- GEMM2': Q[t][r] = H @ W2^T (A rows wave-local, no barrier) ----
        f32x4 c2[2] = {f32x4{0,0,0,0}, f32x4{0,0,0,0}};
        #pragma unroll
        for (int kb = 0; kb < 2; ++kb) {
            bf16x8 af = *(bf16x8*)&hsw[trow * HS_P + 16 * kb + 4 * g];
            #pragma unroll
            for (int nt = 0; nt < 2; ++nt)
                c2[nt] = __builtin_amdgcn_mfma_f32_16x16x32_bf16(
                    af, w2f[nt][kb], c2[nt], 0, 0, 0);
        }

        // ---- exp*m -> asT (b64) + ssum partials via shfl over g ----
        float part0, part1;
        {
            const int tw = 8 * w + 2 * g;          // tokens 16w+4g.. -> word pair
            float a0 = fast_exp(c2[0][0]) * mk.x;
            float a1 = fast_exp(c2[0][1]) * mk.y;
            float a2 = fast_exp(c2[0][2]) * mk.z;
            float a3 = fast_exp(c2[0][3]) * mk.w;
            uint2 u; u.x = pk(a0, a1); u.y = pk(a2, a3);
            *(uint2*)&asw[ml * AS_P + tw] = u;
            part0 = bflo(u.x) + bfhi(u.x) + bflo(u.y) + bfhi(u.y);
            a0 = fast_exp(c2[1][0]) * mk.x;
            a1 = fast_exp(c2[1][1]) * mk.y;
            a2 = fast_exp(c2[1][2]) * mk.z;
            a3 = fast_exp(c2[1][3]) * mk.w;
            u.x = pk(a0, a1); u.y = pk(a2, a3);
            *(uint2*)&asw[(16 + ml) * AS_P + tw] = u;
            part1 = bflo(u.x) + bfhi(u.x) + bflo(u.y) + bfhi(u.y);
        }
        part0 += __shfl_xor(part0, 16); part0 += __shfl_xor(part0, 32);
        part1 += __shfl_xor(part1, 16); part1 += __shfl_xor(part1, 32);
        sswav0 += part0; sswav1 += part1;

        __syncthreads();   // asT + xT (this buffer) visible to all waves

        // ---- GEMM3: acc[r][e] += a^T @ x ----
        {
            const int erow = 16 * w + ml;
            const int esw  = 8 * ((erow >> 3) & 3);
            #pragma unroll
            for (int kb = 0; kb < 2; ++kb) {
                bf16x8 bf = *(bf16x8*)&xtw[erow * XT_P + ((16 * kb + 4 * g) ^ esw)];
                #pragma unroll
                for (int mt = 0; mt < 2; ++mt) {
                    bf16x8 af = *(bf16x8*)&asw[(16 * mt + ml) * AS_P + 16 * kb + 4 * g];
                    c3[mt] = __builtin_amdgcn_mfma_f32_16x16x32_bf16(af, bf, c3[mt], 0, 0, 0);
                }
            }
        }

        gx[0][0] = gxn[0][0]; gx[0][1] = gxn[0][1];
        gx[1][0] = gxn[1][0]; gx[1][1] = gxn[1][1];
        mk = mkn;
    }

    // ---- epilogue ----
    const size_t obase = (size_t)(b * CH_ + c) * (R_ * E_);
    const int e = 16 * w + ml;
    #pragma unroll
    for (int mt = 0; mt < 2; ++mt)
        #pragma unroll
        for (int reg = 0; reg < 4; ++reg) {
            const int r = 16 * mt + 4 * g + reg;
            accp[obase + r * E_ + e] = c3[mt][reg];
        }
    if (g == 0) {
        ssl[w * 32 + ml]      = sswav0;
        ssl[w * 32 + 16 + ml] = sswav1;
    }
    __syncthreads();
    if (tid < 32)
        ssump[(b * CH_ + c) * R_ + tid] =
            ssl[tid] + ssl[32 + tid] + ssl[64 + tid] + ssl[96 + tid];
}

__launch_bounds__(256, 4)
__global__ void selfbi_reduce(const float* __restrict__ accp,
                              const float* __restrict__ ssump,
                              float* __restrict__ out) {
    const int of = blockIdx.x * 256 + threadIdx.x;  // flat (b,r,e)
    const int b  = of >> 11;
    const int o  = of & 2047;
    const int r  = o >> 6;
    float num = 0.f, den = 0.f;
    #pragma unroll
    for (int cc = 0; cc < CH_; ++cc) {
        num += accp[((size_t)(b * CH_ + cc)) * (R_ * E_) + o];
        den += ssump[(b * CH_ + cc) * R_ + r];
    }
    out[of] = num / den;
}

extern "C" void kernel_launch(void* const* d_in, const int* in_sizes, int n_in,
                              void* d_out, int out_size, void* d_ws, size_t ws_size,
                              hipStream_t stream) {
    const float* x    = (const float*)d_in[0];   // (B,L,E)
    const float* mask = (const float*)d_in[1];   // (B,L)
    const float* W1   = (const float*)d_in[2];   // (DA,E)
    const float* W2   = (const float*)d_in[3];   // (R,DA)
    float* out        = (float*)d_out;           // (B,R,E)

    float* accp  = (float*)d_ws;                        // B*CH*R*E fp32
    float* ssump = accp + (size_t)B_ * CH_ * R_ * E_;   // B*CH*R fp32

    selfbi_main<<<dim3(B_, CH_), dim3(256), 0, stream>>>(x, mask, W1, W2, accp, ssump);
    selfbi_reduce<<<dim3((B_ * R_ * E_) / 256), dim3(256), 0, stream>>>(accp, ssump, out);
}

// Round 7
// 207.291 us; speedup vs baseline: 1.1978x; 1.0019x over previous
//
#include <hip/hip_runtime.h>
#include <hip/hip_bf16.h>

// SelfBiLayer B=256,L=2048,E=64,DA=64,R=32 -- MFMA round 7.
// Round-6 model: LDS ISSUE PIPE is the bottleneck (~34 DS ops/wave/sub-chunk
// ~= 42 us busy vs MFMA 4 us, VALU 8 us). Cuts:
//  * hs stored with a d-PERMUTATION chosen so each lane's 16 tanh outputs are
//    CONTIGUOUS -> 2 b128 writes (was 4 b64). W2 register fragments are built
//    with the same permutation (contraction over d is order-agnostic), so
//    GEMM2 is bit-identical. GEMM2 read addresses unchanged.
//  * ssum partials accumulate lane-locally; shfl reduction moved to epilogue
//    (-4 DS-pipe ops per sub-chunk).
//  * CH 8->4 (NS=8): W-frag setup amortized 2x, partial traffic halved.
// Per block: (b, 512-token chunk), 8 sub-chunks of 64 tokens, 4 waves.

#define B_  256
#define L_  2048
#define E_  64
#define DA_ 64
#define R_  32
#define CH_ 4
#define NS_ 8
#define TL_ 64

typedef __attribute__((ext_vector_type(8))) short bf16x8;
typedef __attribute__((ext_vector_type(4))) float f32x4;

// LDS (dword units). Pitches mult-of-4 words keep b128 alignment.
#define HS_P 36
#define XT_P 36
#define AS_P 36
#define HS_W (64 * HS_P)     // 2304
#define XT_W (64 * XT_P)     // 2304 per buffer
#define AS_W (32 * AS_P)     // 1152 per buffer
// hs + 2*xt + 2*as + 128 ssl = 9344 words = 37376 B -> 4 blocks/CU

__device__ __forceinline__ unsigned pk(float a, float b) {
    __hip_bfloat162 h = __float22bfloat162_rn(float2{a, b});
    union { __hip_bfloat162 h2; unsigned u; } cv; cv.h2 = h;
    return cv.u;
}
__device__ __forceinline__ float bflo(unsigned u) { return __uint_as_float(u << 16); }
__device__ __forceinline__ float bfhi(unsigned u) { return __uint_as_float(u & 0xFFFF0000u); }
__device__ __forceinline__ float fast_tanh(float v) {
    float e = __builtin_amdgcn_exp2f(v * 2.885390082f);
    float r = __builtin_amdgcn_rcpf(e + 1.0f);
    return fmaf(-2.0f, r, 1.0f);
}
__device__ __forceinline__ float fast_exp(float v) {
    return __builtin_amdgcn_exp2f(v * 1.442695041f);
}

__launch_bounds__(256, 4)
__global__ void selfbi_main(const float* __restrict__ x,
                            const float* __restrict__ mask,
                            const float* __restrict__ W1,
                            const float* __restrict__ W2,
                            float* __restrict__ accp,
                            float* __restrict__ ssump) {
    __shared__ __align__(16) unsigned smem[HS_W + 2 * XT_W + 2 * AS_W + 128];
    unsigned* hsw  = smem;                       // H token-major, d-PERMUTED slots
    unsigned* xtw0 = smem + HS_W;                // x e-major, double-buffered
    unsigned* asw0 = xtw0 + 2 * XT_W;            // asT[r][t], double-buffered
    float*    ssl  = (float*)(asw0 + 2 * AS_W);  // per-wave ssum partials (epilogue)

    const int b    = blockIdx.x;
    const int c    = blockIdx.y;
    const int tid  = threadIdx.x;
    const int w    = tid >> 6;
    const int lane = tid & 63;
    const int g    = lane >> 4;     // k-octet group
    const int ml   = lane & 15;     // m/n lane

    // ---- W1 A-frags (natural layout) ----
    bf16x8 w1f[4][2];
    #pragma unroll
    for (int mt = 0; mt < 4; ++mt)
        #pragma unroll
        for (int kb = 0; kb < 2; ++kb) {
            const float* p = W1 + (16 * mt + ml) * E_ + 32 * kb + 8 * g;
            float4 a = *(const float4*)p, bb = *(const float4*)(p + 4);
            union { bf16x8 s; unsigned u[4]; } cv;
            cv.u[0] = pk(a.x, a.y); cv.u[1] = pk(a.z, a.w);
            cv.u[2] = pk(bb.x, bb.y); cv.u[3] = pk(bb.z, bb.w);
            w1f[mt][kb] = cv.s;
        }
    // ---- W2^T B-frags, d-PERMUTED to match hs slot layout ----
    // hs slot p (halves) holds d(p) = 16*((p>>2)&3) + 4*(p>>4) + (p&3).
    // Frag elem j reads slot 32kb+8g+j -> d = 16*(2*(g&1)+(j>>2))
    //                                       + 4*(2*kb+(g>>1)) + (j&3).
    bf16x8 w2f[2][2];
    #pragma unroll
    for (int nt = 0; nt < 2; ++nt)
        #pragma unroll
        for (int kb = 0; kb < 2; ++kb) {
            const int dbase = 32 * (g & 1) + 4 * (2 * kb + (g >> 1));
            const float* p = W2 + (16 * nt + ml) * DA_ + dbase;
            float4 a  = *(const float4*)p;          // j=0..3
            float4 bb = *(const float4*)(p + 16);   // j=4..7 (d+16)
            union { bf16x8 s; unsigned u[4]; } cv;
            cv.u[0] = pk(a.x, a.y); cv.u[1] = pk(a.z, a.w);
            cv.u[2] = pk(bb.x, bb.y); cv.u[3] = pk(bb.z, bb.w);
            w2f[nt][kb] = cv.s;
        }

    f32x4 c3[2] = {f32x4{0,0,0,0}, f32x4{0,0,0,0}};
    float sswav0 = 0.0f, sswav1 = 0.0f;   // lane-local; wave-reduced in epilogue

    const int trow  = 16 * w + ml;          // this thread's token within sub-chunk
    const int thalf = trow >> 1, tbyte = trow & 1;
    const size_t cbase = ((size_t)b * L_ + c * (NS_ * TL_)) * E_;
    const int    mbase = b * L_ + c * (NS_ * TL_);

    // ---- prologue: loads for sub-chunk 0 ----
    float4 gx[2][2], mk;
    {
        const float* xr = x + cbase + (size_t)trow * E_ + 8 * g;
        gx[0][0] = *(const float4*)xr;
        gx[0][1] = *(const float4*)(xr + 4);
        gx[1][0] = *(const float4*)(xr + 32);
        gx[1][1] = *(const float4*)(xr + 36);
        mk = *(const float4*)(mask + mbase + 16 * w + 4 * g);
    }

    for (int s = 0; s < NS_; ++s) {
        unsigned* xtw = xtw0 + (s & 1) * XT_W;
        unsigned* asw = asw0 + (s & 1) * AS_W;

        // ---- pack bf16 B-frags for GEMM1 (same values feed xT) ----
        bf16x8 xf[2];
        union { bf16x8 s; unsigned u[4]; } xc[2];
        #pragma unroll
        for (int kb = 0; kb < 2; ++kb) {
            xc[kb].u[0] = pk(gx[kb][0].x, gx[kb][0].y);
            xc[kb].u[1] = pk(gx[kb][0].z, gx[kb][0].w);
            xc[kb].u[2] = pk(gx[kb][1].x, gx[kb][1].y);
            xc[kb].u[3] = pk(gx[kb][1].z, gx[kb][1].w);
            xf[kb] = xc[kb].s;
        }

        // ---- issue NEXT sub-chunk's global loads (hide under GEMM1/2) ----
        float4 gxn[2][2], mkn;
        if (s + 1 < NS_) {
            const float* xr = x + cbase + (size_t)((s + 1) * TL_ + trow) * E_ + 8 * g;
            gxn[0][0] = *(const float4*)xr;
            gxn[0][1] = *(const float4*)(xr + 4);
            gxn[1][0] = *(const float4*)(xr + 32);
            gxn[1][1] = *(const float4*)(xr + 36);
            mkn = *(const float4*)(mask + mbase + (s + 1) * TL_ + 16 * w + 4 * g);
        }

        // ---- xT: e-major, token-column scatter, swizzle word^(8g) ----
        #pragma unroll
        for (int kb = 0; kb < 2; ++kb)
            #pragma unroll
            for (int i = 0; i < 4; ++i) {
                const int e0 = 32 * kb + 8 * g + 2 * i;
                const int wd = thalf ^ (8 * g);
                ((unsigned short*)&xtw[e0 * XT_P + wd])[tbyte] =
                    (unsigned short)(xc[kb].u[i] & 0xFFFF);
                ((unsigned short*)&xtw[(e0 + 1) * XT_P + wd])[tbyte] =
                    (unsigned short)(xc[kb].u[i] >> 16);
            }

        // ---- GEMM1: H^T tile (this wave's 16 tokens) ----
        f32x4 c1[4] = {f32x4{0,0,0,0}, f32x4{0,0,0,0}, f32x4{0,0,0,0}, f32x4{0,0,0,0}};
        #pragma unroll
        for (int kb = 0; kb < 2; ++kb)
            #pragma unroll
            for (int mt = 0; mt < 4; ++mt)
                c1[mt] = __builtin_amdgcn_mfma_f32_16x16x32_bf16(
                    w1f[mt][kb], xf[kb], c1[mt], 0, 0, 0);

        // ---- tanh -> hs: lane's 16 values CONTIGUOUS (2 b128 writes) ----
        // slot halves [16g .. 16g+16): p = 16g + 4mt + reg
        {
            float th[4][4];
            #pragma unroll
            for (int mt = 0; mt < 4; ++mt)
                #pragma unroll
                for (int reg = 0; reg < 4; ++reg)
                    th[mt][reg] = fast_tanh(c1[mt][reg]);
            uint4 ua, ub;
            ua.x = pk(th[0][0], th[0][1]); ua.y = pk(th[0][2], th[0][3]);
            ua.z = pk(th[1][0], th[1][1]); ua.w = pk(th[1][2], th[1][3]);
            ub.x = pk(th[2][0], th[2][1]); ub.y = pk(th[2][2], th[2][3]);
            ub.z = pk(th[3][0], th[3][1]); ub.w = pk(th[3][2], th[3][3]);
            *(uint4*)&hsw[trow * HS_P + 8 * g]     = ua;
            *(uint4*)&hsw[trow * HS_P + 8 * g + 4] = ub;
        }

        // ---- GEMM2': Q[t][r] = H @ W2^T (permutation-matched frags) ----
        f32x4 c2[2] = {f32x4{0,0,0,0}, f32x4{0,0,0,0}};
        #pragma unroll
        for (int kb = 0; kb < 2; ++kb) {
            bf16x8 af = *(bf16x8*)&hsw[trow * HS_P + 16 * kb + 4 * g];
            #pragma unroll
            for (int nt = 0; nt < 2; ++nt)
                c2[nt] = __builtin_amdgcn_mfma_f32_16x16x32_bf16(
                    af, w2f[nt][kb], c2[nt], 0, 0, 0);
        }

        // ---- exp*m -> asT (b64) + lane-local ssum partials ----
        {
            const int tw = 8 * w + 2 * g;          // tokens 16w+4g.. -> word pair
            float a0 = fast_exp(c2[0][0]) * mk.x;
            float a1 = fast_exp(c2[0][1]) * mk.y;
            float a2 = fast_exp(c2[0][2]) * mk.z;
            float a3 = fast_exp(c2[0][3]) * mk.w;
            uint2 u; u.x = pk(a0, a1); u.y = pk(a2, a3);
            *(uint2*)&asw[ml * AS_P + tw] = u;
            sswav0 += bflo(u.x) + bfhi(u.x) + bflo(u.y) + bfhi(u.y);
            a0 = fast_exp(c2[1][0]) * mk.x;
            a1 = fast_exp(c2[1][1]) * mk.y;
            a2 = fast_exp(c2[1][2]) * mk.z;
            a3 = fast_exp(c2[1][3]) * mk.w;
            u.x = pk(a0, a1); u.y = pk(a2, a3);
            *(uint2*)&asw[(16 + ml) * AS_P + tw] = u;
            sswav1 += bflo(u.x) + bfhi(u.x) + bflo(u.y) + bfhi(u.y);
        }

        __syncthreads();   // asT + xT (this buffer) visible to all waves

        // ---- GEMM3: acc[r][e] += a^T @ x ----
        {
            const int erow = 16 * w + ml;
            const int esw  = 8 * ((erow >> 3) & 3);
            #pragma unroll
            for (int kb = 0; kb < 2; ++kb) {
                bf16x8 bf = *(bf16x8*)&xtw[erow * XT_P + ((16 * kb + 4 * g) ^ esw)];
                #pragma unroll
                for (int mt = 0; mt < 2; ++mt) {
                    bf16x8 af = *(bf16x8*)&asw[(16 * mt + ml) * AS_P + 16 * kb + 4 * g];
                    c3[mt] = __builtin_amdgcn_mfma_f32_16x16x32_bf16(af, bf, c3[mt], 0, 0, 0);
                }
            }
        }

        gx[0][0] = gxn[0][0]; gx[0][1] = gxn[0][1];
        gx[1][0] = gxn[1][0]; gx[1][1] = gxn[1][1];
        mk = mkn;
    }

    // ---- epilogue ----
    // ssum: reduce over g (lane bits 4,5), then across waves via ssl.
    sswav0 += __shfl_xor(sswav0, 16); sswav0 += __shfl_xor(sswav0, 32);
    sswav1 += __shfl_xor(sswav1, 16); sswav1 += __shfl_xor(sswav1, 32);

    const size_t obase = (size_t)(b * CH_ + c) * (R_ * E_);
    const int e = 16 * w + ml;
    #pragma unroll
    for (int mt = 0; mt < 2; ++mt)
        #pragma unroll
        for (int reg = 0; reg < 4; ++reg) {
            const int r = 16 * mt + 4 * g + reg;
            accp[obase + r * E_ + e] = c3[mt][reg];
        }
    if (g == 0) {
        ssl[w * 32 + ml]      = sswav0;
        ssl[w * 32 + 16 + ml] = sswav1;
    }
    __syncthreads();
    if (tid < 32)
        ssump[(b * CH_ + c) * R_ + tid] =
            ssl[tid] + ssl[32 + tid] + ssl[64 + tid] + ssl[96 + tid];
}

__launch_bounds__(256, 4)
__global__ void selfbi_reduce(const float* __restrict__ accp,
                              const float* __restrict__ ssump,
                              float* __restrict__ out) {
    const int of = blockIdx.x * 256 + threadIdx.x;  // flat (b,r,e)
    const int b  = of >> 11;
    const int o  = of & 2047;
    const int r  = o >> 6;
    float num = 0.f, den = 0.f;
    #pragma unroll
    for (int cc = 0; cc < CH_; ++cc) {
        num += accp[((size_t)(b * CH_ + cc)) * (R_ * E_) + o];
        den += ssump[(b * CH_ + cc) * R_ + r];
    }
    out[of] = num / den;
}

extern "C" void kernel_launch(void* const* d_in, const int* in_sizes, int n_in,
                              void* d_out, int out_size, void* d_ws, size_t ws_size,
                              hipStream_t stream) {
    const float* x    = (const float*)d_in[0];   // (B,L,E)
    const float* mask = (const float*)d_in[1];   // (B,L)
    const float* W1   = (const float*)d_in[2];   // (DA,E)
    const float* W2   = (const float*)d_in[3];   // (R,DA)
    float* out        = (float*)d_out;           // (B,R,E)

    float* accp  = (float*)d_ws;                        // B*CH*R*E fp32 = 8.4 MB
    float* ssump = accp + (size_t)B_ * CH_ * R_ * E_;   // B*CH*R fp32

    selfbi_main<<<dim3(B_, CH_), dim3(256), 0, stream>>>(x, mask, W1, W2, accp, ssump);
    selfbi_reduce<<<dim3((B_ * R_ * E_) / 256), dim3(256), 0, stream>>>(accp, ssump, out);
}